// Round 5
// baseline (169.698 us; speedup 1.0000x reference)
//
#include <hip/hip_runtime.h>
#include <math.h>

#define Nn 64
#define Tt 200
#define Bb 64

__device__ __forceinline__ float sigm(float x){ return 1.0f/(1.0f+__expf(-x)); }
__device__ __forceinline__ float tanh_fast(float x){
  x = fminf(fmaxf(x, -15.f), 15.f);
  float e = __expf(-2.f*x);
  return (1.f - e)/(1.f + e);
}

typedef __attribute__((ext_vector_type(4))) float f4;

// Raw workgroup barrier: drain LDS only (s_waitcnt lgkmcnt(0)), NOT vmcnt.
// __syncthreads() emits s_waitcnt vmcnt(0) which would serialize the global
// xp prefetch + gru_out stores into every step (the m97 barrier-drain trap).
// sched_barrier(0) on both sides per rule #18 (stop LDS reads hoisting).
#define BAR_LGKM() do {                                   \
    __builtin_amdgcn_sched_barrier(0);                    \
    asm volatile("s_waitcnt lgkmcnt(0)" ::: "memory");    \
    __builtin_amdgcn_s_barrier();                         \
    __builtin_amdgcn_sched_barrier(0);                    \
  } while (0)

// ---------------------------------------------------------------------------
// K1: build graph operators. L = -S_cheb, L2 = 2*S@S - I, G = S_gcn (+diag).
// Single block, 256 threads. Edge scatter via LDS atomics; S padded to
// stride 68 so the S@S phase uses conflict-free f4 row reads.
// ---------------------------------------------------------------------------
__global__ __launch_bounds__(256) void k1_graphs(
    const int* __restrict__ sp_ei, const float* __restrict__ sp_ew,
    const int* __restrict__ fn_ei, const float* __restrict__ fn_ew,
    float* __restrict__ Lg, float* __restrict__ L2g, float* __restrict__ Gm)
{
  __shared__ float deg[Nn];
  __shared__ float dinv[Nn];
  __shared__ float S[64*68];            // padded stride 68
  const int tid = threadIdx.x;

  // ---- ChebConv operator (512 edges) ----
  if (tid < Nn) deg[tid] = 0.f;
  for (int i=tid;i<64*68;i+=256) S[i]=0.f;
  __syncthreads();
  for (int e=tid;e<512;e+=256) atomicAdd(&deg[sp_ei[e]], sp_ew[e]);   // deg over row
  __syncthreads();
  if (tid < Nn) dinv[tid] = (deg[tid] > 0.f) ? rsqrtf(deg[tid]) : 0.f;
  __syncthreads();
  for (int e=tid;e<512;e+=256) {
    int r = sp_ei[e], c = sp_ei[512+e];
    atomicAdd(&S[c*68 + r], dinv[r]*sp_ew[e]*dinv[c]);
  }
  __syncthreads();
  for (int i=tid;i<4096;i+=256) Lg[i] = -S[(i>>6)*68 + (i&63)];   // Ltil = -S
  // L2 = 2*S@S - I : thread -> row n = tid>>2, 16 cols at mb=(tid&3)*16
  {
    const int n = tid>>2, mb = (tid&3)*16;
    float a[16];
    #pragma unroll
    for (int q=0;q<16;q++) a[q]=0.f;
    for (int j=0;j<64;j++){
      float snj = S[n*68+j];
      const float4* rj = (const float4*)&S[j*68+mb];
      #pragma unroll
      for (int q=0;q<4;q++){
        float4 v = rj[q];
        a[q*4+0]=fmaf(snj,v.x,a[q*4+0]);
        a[q*4+1]=fmaf(snj,v.y,a[q*4+1]);
        a[q*4+2]=fmaf(snj,v.z,a[q*4+2]);
        a[q*4+3]=fmaf(snj,v.w,a[q*4+3]);
      }
    }
    #pragma unroll
    for (int q=0;q<16;q++){
      int m = mb+q;
      L2g[n*64+m] = 2.f*a[q] - (n==m ? 1.f : 0.f);
    }
  }
  __syncthreads();   // all reads of S done before reuse

  // ---- GCNConv operator (1024 edges) ----
  if (tid < Nn) deg[tid] = 0.f;
  for (int i=tid;i<64*68;i+=256) S[i]=0.f;
  __syncthreads();
  for (int e=tid;e<1024;e+=256) atomicAdd(&deg[fn_ei[1024+e]], fn_ew[e]);  // deg over col
  __syncthreads();
  if (tid < Nn) dinv[tid] = rsqrtf(deg[tid] + 1.f);
  __syncthreads();
  for (int e=tid;e<1024;e+=256) {
    int r = fn_ei[e], c = fn_ei[1024+e];
    atomicAdd(&S[c*68 + r], dinv[r]*fn_ew[e]*dinv[c]);
  }
  __syncthreads();
  if (tid < Nn) S[tid*68 + tid] += dinv[tid]*dinv[tid];     // + diag(1/deg)
  __syncthreads();
  for (int i=tid;i<4096;i+=256) Gm[i] = S[(i>>6)*68 + (i&63)];
}

// ---------------------------------------------------------------------------
// K2: fold Wih (+Wcheb/Wgcn/graph ops) into Aeff[384][64] and constv[384].
// ---------------------------------------------------------------------------
__global__ __launch_bounds__(64) void k2_aeff(
    const float* __restrict__ Wih_f, const float* __restrict__ bih_f,
    const float* __restrict__ Wih_b, const float* __restrict__ bih_b,
    const float* __restrict__ Wcheb, const float* __restrict__ bcheb,
    const float* __restrict__ Wgcn,  const float* __restrict__ bgcn,
    const float* __restrict__ Lg, const float* __restrict__ L2g,
    const float* __restrict__ Gm,
    float* __restrict__ Aeff, float* __restrict__ constv)
{
  const int g = blockIdx.x;                 // 0..383
  const int dir = (g >= 192) ? 1 : 0;
  const int grow = dir ? g - 192 : g;
  const float* Wih = dir ? Wih_b : Wih_f;
  const float* bih = dir ? bih_b : bih_f;

  __shared__ float wrow[64*129];
  __shared__ float arow[256];
  const int tid = threadIdx.x;              // 64 threads = 1 wave

  for (int i = tid; i < 8192; i += 64)
    wrow[(i>>7)*129 + (i&127)] = Wih[grow*8192 + i];
  __syncthreads();

  const int n = tid;
  float a0=0.f,a1=0.f,a2=0.f,a3=0.f,cp=0.f;
  for (int c=0;c<64;c++) {
    float w1 = wrow[n*129 + c];
    a0 = fmaf(w1, Wcheb[c],     a0);
    a1 = fmaf(w1, Wcheb[64+c],  a1);
    a2 = fmaf(w1, Wcheb[128+c], a2);
    cp = fmaf(w1, bcheb[c],     cp);
    float w2 = wrow[n*129 + 64 + c];
    a3 = fmaf(w2, Wgcn[c], a3);
    cp = fmaf(w2, bgcn[c], cp);
  }
  arow[n*4+0]=a0; arow[n*4+1]=a1; arow[n*4+2]=a2; arow[n*4+3]=a3;
  for (int off=32; off; off>>=1) cp += __shfl_down(cp, off, 64);
  if (tid==0) constv[g] = cp + bih[grow];
  __syncthreads();

  const int m = tid;
  float ae = arow[m*4+0];
  for (int nn2=0; nn2<64; nn2++) {
    ae = fmaf(arow[nn2*4+1], Lg [nn2*64+m], ae);
    ae = fmaf(arow[nn2*4+2], L2g[nn2*64+m], ae);
    ae = fmaf(arow[nn2*4+3], Gm [nn2*64+m], ae);
  }
  Aeff[g*64+m] = ae;
}

// ---------------------------------------------------------------------------
// K3: transpose x[B][N][T] -> xTr[B*T][N]
// ---------------------------------------------------------------------------
__global__ __launch_bounds__(256) void k3_transpose(
    const float* __restrict__ x, float* __restrict__ xTr)
{
  const int b = blockIdx.x;
  for (int idx = threadIdx.x; idx < Tt*Nn; idx += 256) {
    int t = idx >> 6, m = idx & 63;
    xTr[(b*Tt + t)*64 + m] = x[(b*64 + m)*Tt + t];
  }
}

// ---------------------------------------------------------------------------
// K4: xp[12800][384] = xTr[12800][64] @ Aeff[384][64]^T + constv
// ---------------------------------------------------------------------------
__global__ __launch_bounds__(256) void k4_gemm(
    const float* __restrict__ xTr, const float* __restrict__ Aeff,
    const float* __restrict__ constv, float* __restrict__ xp)
{
  const int m0 = blockIdx.x*64, g0 = blockIdx.y*64;
  __shared__ float sX[64*68];
  __shared__ float sA[64*68];
  const int tid = threadIdx.x;
  const float4* xTr4 = (const float4*)xTr;
  const float4* A4   = (const float4*)Aeff;

  #pragma unroll
  for (int i=0;i<4;i++) {
    int f = tid + i*256;
    int row = f >> 4, kq = f & 15;
    float4 v = xTr4[(m0+row)*16 + kq];
    float vv[4] = {v.x,v.y,v.z,v.w};
    float4 w = A4[(g0+row)*16 + kq];
    float wv[4] = {w.x,w.y,w.z,w.w};
    #pragma unroll
    for (int q=0;q<4;q++) {
      sX[(kq*4+q)*68 + row] = vv[q];
      sA[(kq*4+q)*68 + row] = wv[q];
    }
  }
  __syncthreads();

  const int tm = tid & 15, tn = tid >> 4;
  float acc[4][4] = {};
  #pragma unroll 8
  for (int k=0;k<64;k++) {
    float4 a  = *(const float4*)&sX[k*68 + tm*4];
    float4 bb = *(const float4*)&sA[k*68 + tn*4];
    float av[4]={a.x,a.y,a.z,a.w}, bv[4]={bb.x,bb.y,bb.z,bb.w};
    #pragma unroll
    for (int i=0;i<4;i++)
      #pragma unroll
      for (int j=0;j<4;j++)
        acc[i][j] = fmaf(av[i], bv[j], acc[i][j]);
  }

  float cv[4];
  #pragma unroll
  for (int j=0;j<4;j++) cv[j] = constv[g0 + tn*4 + j];
  #pragma unroll
  for (int i=0;i<4;i++) {
    int mrow = m0 + tm*4 + i;
    #pragma unroll
    for (int j=0;j<4;j++)
      xp[mrow*384 + g0 + tn*4 + j] = acc[i][j] + cv[j];
  }
}

// ---------------------------------------------------------------------------
// K5: biGRU recurrence. 128 blocks = (b, dir); 192 threads (3 waves).
// Thread g owns ONE gate row (64 fp32 weights resident in VGPRs). h broadcast
// via LDS b128 reads; gates on wave 0; gru_out store on wave 1 (off the
// critical wave). Step-loop barriers are RAW s_barrier + lgkmcnt(0) only, so
// the depth-2 xp prefetch and the gru_out stores stay in flight across
// barriers (counted vmcnt waits at use, never a vmcnt(0) drain).
// ---------------------------------------------------------------------------
__global__ __launch_bounds__(192, 1) void k5_gru(
    const float* __restrict__ xp,
    const float* __restrict__ Whh_f, const float* __restrict__ bhh_f,
    const float* __restrict__ Whh_b, const float* __restrict__ bhh_b,
    float* __restrict__ gru_out)
{
  const int bd = blockIdx.x;
  const int b = bd >> 1, dir = bd & 1;
  const int g = threadIdx.x;                // 0..191
  const float* Whh = dir ? Whh_b : Whh_f;
  const float* bhh = dir ? bhh_b : bhh_f;

  f4 w[16];
  #pragma unroll
  for (int j=0;j<16;j++) w[j] = ((const f4*)(Whh + g*64))[j];
  const float bh = bhh[g];

  __shared__ __align__(16) float h_s[64];
  __shared__ float hg_s[192];
  __shared__ float xn_s[64];
  const f4* h4 = (const f4*)h_s;

  float hprev = 0.f;
  if (g < 64) h_s[g] = 0.f;

  const int t0 = dir ? (Tt-1) : 0;
  const int tstep = dir ? -1 : 1;
  const float* xbase = xp + ((size_t)b*Tt)*384 + dir*192 + g;
  float* gout1 = gru_out + ((size_t)b*Tt)*128 + dir*64 + (g-64);  // wave1 lanes

  float xqA = xbase[(size_t)t0*384];
  float xqB = xbase[(size_t)(t0+tstep)*384];
  __syncthreads();                      // one-time: h_s=0 + initial prefetch

  int t = t0;
  auto STEP = [&](float& xq) {
    // ---- matvec: hg[g] = w . h  (4 independent FMA chains) ----
    float a0=0.f,a1=0.f,a2=0.f,a3=0.f;
    #pragma unroll
    for (int j=0;j<4;j++){
      f4 w0=w[4*j], w1=w[4*j+1], w2=w[4*j+2], w3=w[4*j+3];
      f4 h0=h4[4*j], h1=h4[4*j+1], h2=h4[4*j+2], h3=h4[4*j+3];
      a0=fmaf(w0.x,h0.x,a0); a0=fmaf(w0.y,h0.y,a0); a0=fmaf(w0.z,h0.z,a0); a0=fmaf(w0.w,h0.w,a0);
      a1=fmaf(w1.x,h1.x,a1); a1=fmaf(w1.y,h1.y,a1); a1=fmaf(w1.z,h1.z,a1); a1=fmaf(w1.w,h1.w,a1);
      a2=fmaf(w2.x,h2.x,a2); a2=fmaf(w2.y,h2.y,a2); a2=fmaf(w2.z,h2.z,a2); a2=fmaf(w2.w,h2.w,a2);
      a3=fmaf(w3.x,h3.x,a3); a3=fmaf(w3.y,h3.y,a3); a3=fmaf(w3.z,h3.z,a3); a3=fmaf(w3.w,h3.w,a3);
    }
    float pre = ((a0+a1)+(a2+a3)) + bh;
    if (g < 128) pre += xq;           // r,z gates: x-part folded in
    else xn_s[g-128] = xq;            // n gate: x-part kept separate
    hg_s[g] = pre;

    // reload this register for step s+2 (stays in flight across barriers)
    int tpre = t + 2*tstep;
    if ((unsigned)tpre < (unsigned)Tt) xq = xbase[(size_t)tpre*384];

    BAR_LGKM();                       // hg_s/xn_s visible; vmem NOT drained
    if (g < 64) {
      float r   = sigm(hg_s[g]);
      float z   = sigm(hg_s[64+g]);
      float nng = tanh_fast(xn_s[g] + r*hg_s[128+g]);
      float hnew = (1.f-z)*nng + z*hprev;
      hprev = hnew;
      h_s[g] = hnew;
    }
    BAR_LGKM();                       // h_s visible; vmem NOT drained
    if (g >= 64 && g < 128) {         // wave 1: store h off the critical wave
      gout1[(size_t)t*128] = h_s[g-64];
    }
    t += tstep;
  };

  for (int sp=0; sp<Tt; sp+=2) {
    STEP(xqA);
    STEP(xqB);
  }
}

// ---------------------------------------------------------------------------
// K6: attention pooling + classifier. One block per batch item.
// ---------------------------------------------------------------------------
__global__ __launch_bounds__(256) void k6_attn(
    const float* __restrict__ gru_out,
    const float* __restrict__ attn_W, const float* __restrict__ attn_b,
    const float* __restrict__ clf_W,  const float* __restrict__ clf_b,
    float* __restrict__ out)
{
  const int b = blockIdx.x, tid = threadIdx.x;
  __shared__ float s_s[Tt];
  __shared__ float red[256];
  __shared__ float aW[128], cW[128];
  if (tid < 128) { aW[tid]=attn_W[tid]; cW[tid]=clf_W[tid]; }
  __syncthreads();

  if (tid < Tt) {
    const float* row = gru_out + (b*Tt + tid)*128;
    float acc = 0.f;
    for (int j=0;j<128;j++) acc = fmaf(row[j], aW[j], acc);
    s_s[tid] = tanhf(acc + attn_b[0]);
  }
  __syncthreads();

  red[tid] = (tid < Tt) ? s_s[tid] : -1e30f;
  __syncthreads();
  for (int s2=128;s2;s2>>=1){ if(tid<s2) red[tid]=fmaxf(red[tid],red[tid+s2]); __syncthreads(); }
  float mx = red[0];
  __syncthreads();

  float e = 0.f;
  if (tid < Tt) { e = expf(s_s[tid]-mx); s_s[tid] = e; }
  red[tid] = e;
  __syncthreads();
  for (int s2=128;s2;s2>>=1){ if(tid<s2) red[tid]+=red[tid+s2]; __syncthreads(); }
  float total = red[0];
  __syncthreads();

  float p = 0.f;
  if (tid < 128) {
    float c = 0.f;
    for (int t=0;t<Tt;t++) c = fmaf(s_s[t], gru_out[(b*Tt+t)*128 + tid], c);
    p = (c/total)*cW[tid];
  }
  red[tid] = p;
  __syncthreads();
  for (int s2=128;s2;s2>>=1){ if(tid<s2) red[tid]+=red[tid+s2]; __syncthreads(); }
  if (tid==0) out[b] = sigm(red[0] + clf_b[0]);
}

// ---------------------------------------------------------------------------
extern "C" void kernel_launch(void* const* d_in, const int* in_sizes, int n_in,
                              void* d_out, int out_size, void* d_ws, size_t ws_size,
                              hipStream_t stream)
{
  const float* x      = (const float*)d_in[0];
  const int*   sp_ei  = (const int*)  d_in[1];
  const float* sp_ew  = (const float*)d_in[2];
  const int*   fn_ei  = (const int*)  d_in[3];
  const float* fn_ew  = (const float*)d_in[4];
  const float* Wcheb  = (const float*)d_in[5];
  const float* bcheb  = (const float*)d_in[6];
  const float* Wgcn   = (const float*)d_in[7];
  const float* bgcn   = (const float*)d_in[8];
  const float* Wih_f  = (const float*)d_in[9];
  const float* Whh_f  = (const float*)d_in[10];
  const float* bih_f  = (const float*)d_in[11];
  const float* bhh_f  = (const float*)d_in[12];
  const float* Wih_b  = (const float*)d_in[13];
  const float* Whh_b  = (const float*)d_in[14];
  const float* bih_b  = (const float*)d_in[15];
  const float* bhh_b  = (const float*)d_in[16];
  const float* attn_W = (const float*)d_in[17];
  const float* attn_b = (const float*)d_in[18];
  const float* clf_W  = (const float*)d_in[19];
  const float* clf_b  = (const float*)d_in[20];
  float* out = (float*)d_out;

  float* ws     = (float*)d_ws;
  float* Lg     = ws;                    // 4096
  float* L2g    = Lg   + 4096;           // 4096
  float* Gm     = L2g  + 4096;           // 4096
  float* Aeff   = Gm   + 4096;           // 384*64 = 24576
  float* constv = Aeff + 24576;          // 384 (+pad to 512)
  float* xTr    = constv + 512;          // 12800*64 = 819200
  float* xp     = xTr  + 819200;         // 12800*384 = 4915200
  float* gro    = xp   + 4915200;        // 12800*128 = 1638400

  hipLaunchKernelGGL(k1_graphs,    dim3(1),      dim3(256), 0, stream,
                     sp_ei, sp_ew, fn_ei, fn_ew, Lg, L2g, Gm);
  hipLaunchKernelGGL(k3_transpose, dim3(64),     dim3(256), 0, stream, x, xTr);
  hipLaunchKernelGGL(k2_aeff,      dim3(384),    dim3(64),  0, stream,
                     Wih_f, bih_f, Wih_b, bih_b, Wcheb, bcheb, Wgcn, bgcn,
                     Lg, L2g, Gm, Aeff, constv);
  hipLaunchKernelGGL(k4_gemm,      dim3(200, 6), dim3(256), 0, stream,
                     xTr, Aeff, constv, xp);
  hipLaunchKernelGGL(k5_gru,       dim3(128),    dim3(192), 0, stream,
                     xp, Whh_f, bhh_f, Whh_b, bhh_b, gro);
  hipLaunchKernelGGL(k6_attn,      dim3(64),     dim3(256), 0, stream,
                     gro, attn_W, attn_b, clf_W, clf_b, out);
}

// Round 6
// 168.954 us; speedup vs baseline: 1.0044x; 1.0044x over previous
//
#include <hip/hip_runtime.h>
#include <math.h>

#define Nn 64
#define Tt 200
#define Bb 64

__device__ __forceinline__ float sigm(float x){ return 1.0f/(1.0f+__expf(-x)); }
__device__ __forceinline__ float tanh_fast(float x){
  x = fminf(fmaxf(x, -15.f), 15.f);
  float e = __expf(-2.f*x);
  return (1.f - e)/(1.f + e);
}

typedef __attribute__((ext_vector_type(2))) _Float16 h2v;
typedef __attribute__((ext_vector_type(4))) float f4;

// fp16 dot2 with fp32 accumulate (v_dot2_f32_f16). Fallback: cvt+fma pair.
#if __has_builtin(__builtin_amdgcn_fdot2)
#define DOT2(w,hv,acc) __builtin_amdgcn_fdot2((w),(hv),(acc),false)
#else
#define DOT2(w,hv,acc) fmaf((float)(w)[0],(float)(hv)[0], fmaf((float)(w)[1],(float)(hv)[1],(acc)))
#endif

// ---------------------------------------------------------------------------
// K1: build graph operators. L = -S_cheb, L2 = 2*S@S - I, G = S_gcn (+diag).
// Single block, 256 threads. Edge scatter via LDS atomics; S padded to
// stride 68 so the S@S phase uses conflict-free f4 row reads.
// ---------------------------------------------------------------------------
__global__ __launch_bounds__(256) void k1_graphs(
    const int* __restrict__ sp_ei, const float* __restrict__ sp_ew,
    const int* __restrict__ fn_ei, const float* __restrict__ fn_ew,
    float* __restrict__ Lg, float* __restrict__ L2g, float* __restrict__ Gm)
{
  __shared__ float deg[Nn];
  __shared__ float dinv[Nn];
  __shared__ float S[64*68];            // padded stride 68
  const int tid = threadIdx.x;

  // ---- ChebConv operator (512 edges) ----
  if (tid < Nn) deg[tid] = 0.f;
  for (int i=tid;i<64*68;i+=256) S[i]=0.f;
  __syncthreads();
  for (int e=tid;e<512;e+=256) atomicAdd(&deg[sp_ei[e]], sp_ew[e]);   // deg over row
  __syncthreads();
  if (tid < Nn) dinv[tid] = (deg[tid] > 0.f) ? rsqrtf(deg[tid]) : 0.f;
  __syncthreads();
  for (int e=tid;e<512;e+=256) {
    int r = sp_ei[e], c = sp_ei[512+e];
    atomicAdd(&S[c*68 + r], dinv[r]*sp_ew[e]*dinv[c]);
  }
  __syncthreads();
  for (int i=tid;i<4096;i+=256) Lg[i] = -S[(i>>6)*68 + (i&63)];   // Ltil = -S
  // L2 = 2*S@S - I : thread -> row n = tid>>2, 16 cols at mb=(tid&3)*16
  {
    const int n = tid>>2, mb = (tid&3)*16;
    float a[16];
    #pragma unroll
    for (int q=0;q<16;q++) a[q]=0.f;
    for (int j=0;j<64;j++){
      float snj = S[n*68+j];
      const float4* rj = (const float4*)&S[j*68+mb];
      #pragma unroll
      for (int q=0;q<4;q++){
        float4 v = rj[q];
        a[q*4+0]=fmaf(snj,v.x,a[q*4+0]);
        a[q*4+1]=fmaf(snj,v.y,a[q*4+1]);
        a[q*4+2]=fmaf(snj,v.z,a[q*4+2]);
        a[q*4+3]=fmaf(snj,v.w,a[q*4+3]);
      }
    }
    #pragma unroll
    for (int q=0;q<16;q++){
      int m = mb+q;
      L2g[n*64+m] = 2.f*a[q] - (n==m ? 1.f : 0.f);
    }
  }
  __syncthreads();   // all reads of S done before reuse

  // ---- GCNConv operator (1024 edges) ----
  if (tid < Nn) deg[tid] = 0.f;
  for (int i=tid;i<64*68;i+=256) S[i]=0.f;
  __syncthreads();
  for (int e=tid;e<1024;e+=256) atomicAdd(&deg[fn_ei[1024+e]], fn_ew[e]);  // deg over col
  __syncthreads();
  if (tid < Nn) dinv[tid] = rsqrtf(deg[tid] + 1.f);
  __syncthreads();
  for (int e=tid;e<1024;e+=256) {
    int r = fn_ei[e], c = fn_ei[1024+e];
    atomicAdd(&S[c*68 + r], dinv[r]*fn_ew[e]*dinv[c]);
  }
  __syncthreads();
  if (tid < Nn) S[tid*68 + tid] += dinv[tid]*dinv[tid];     // + diag(1/deg)
  __syncthreads();
  for (int i=tid;i<4096;i+=256) Gm[i] = S[(i>>6)*68 + (i&63)];
}

// ---------------------------------------------------------------------------
// K2: fold Wih (+Wcheb/Wgcn/graph ops) into Aeff[384][64] and constv[384].
// ---------------------------------------------------------------------------
__global__ __launch_bounds__(64) void k2_aeff(
    const float* __restrict__ Wih_f, const float* __restrict__ bih_f,
    const float* __restrict__ Wih_b, const float* __restrict__ bih_b,
    const float* __restrict__ Wcheb, const float* __restrict__ bcheb,
    const float* __restrict__ Wgcn,  const float* __restrict__ bgcn,
    const float* __restrict__ Lg, const float* __restrict__ L2g,
    const float* __restrict__ Gm,
    float* __restrict__ Aeff, float* __restrict__ constv)
{
  const int g = blockIdx.x;                 // 0..383
  const int dir = (g >= 192) ? 1 : 0;
  const int grow = dir ? g - 192 : g;
  const float* Wih = dir ? Wih_b : Wih_f;
  const float* bih = dir ? bih_b : bih_f;

  __shared__ float wrow[64*129];
  __shared__ float arow[256];
  const int tid = threadIdx.x;              // 64 threads = 1 wave

  for (int i = tid; i < 8192; i += 64)
    wrow[(i>>7)*129 + (i&127)] = Wih[grow*8192 + i];
  __syncthreads();

  const int n = tid;
  float a0=0.f,a1=0.f,a2=0.f,a3=0.f,cp=0.f;
  for (int c=0;c<64;c++) {
    float w1 = wrow[n*129 + c];
    a0 = fmaf(w1, Wcheb[c],     a0);
    a1 = fmaf(w1, Wcheb[64+c],  a1);
    a2 = fmaf(w1, Wcheb[128+c], a2);
    cp = fmaf(w1, bcheb[c],     cp);
    float w2 = wrow[n*129 + 64 + c];
    a3 = fmaf(w2, Wgcn[c], a3);
    cp = fmaf(w2, bgcn[c], cp);
  }
  arow[n*4+0]=a0; arow[n*4+1]=a1; arow[n*4+2]=a2; arow[n*4+3]=a3;
  for (int off=32; off; off>>=1) cp += __shfl_down(cp, off, 64);
  if (tid==0) constv[g] = cp + bih[grow];
  __syncthreads();

  const int m = tid;
  float ae = arow[m*4+0];
  for (int nn2=0; nn2<64; nn2++) {
    ae = fmaf(arow[nn2*4+1], Lg [nn2*64+m], ae);
    ae = fmaf(arow[nn2*4+2], L2g[nn2*64+m], ae);
    ae = fmaf(arow[nn2*4+3], Gm [nn2*64+m], ae);
  }
  Aeff[g*64+m] = ae;
}

// ---------------------------------------------------------------------------
// K3: transpose x[B][N][T] -> xTr[B*T][N]
// ---------------------------------------------------------------------------
__global__ __launch_bounds__(256) void k3_transpose(
    const float* __restrict__ x, float* __restrict__ xTr)
{
  const int b = blockIdx.x;
  for (int idx = threadIdx.x; idx < Tt*Nn; idx += 256) {
    int t = idx >> 6, m = idx & 63;
    xTr[(b*Tt + t)*64 + m] = x[(b*64 + m)*Tt + t];
  }
}

// ---------------------------------------------------------------------------
// K4: xp[12800][384] = xTr[12800][64] @ Aeff[384][64]^T + constv
// ---------------------------------------------------------------------------
__global__ __launch_bounds__(256) void k4_gemm(
    const float* __restrict__ xTr, const float* __restrict__ Aeff,
    const float* __restrict__ constv, float* __restrict__ xp)
{
  const int m0 = blockIdx.x*64, g0 = blockIdx.y*64;
  __shared__ float sX[64*68];
  __shared__ float sA[64*68];
  const int tid = threadIdx.x;
  const float4* xTr4 = (const float4*)xTr;
  const float4* A4   = (const float4*)Aeff;

  #pragma unroll
  for (int i=0;i<4;i++) {
    int f = tid + i*256;
    int row = f >> 4, kq = f & 15;
    float4 v = xTr4[(m0+row)*16 + kq];
    float vv[4] = {v.x,v.y,v.z,v.w};
    float4 w = A4[(g0+row)*16 + kq];
    float wv[4] = {w.x,w.y,w.z,w.w};
    #pragma unroll
    for (int q=0;q<4;q++) {
      sX[(kq*4+q)*68 + row] = vv[q];
      sA[(kq*4+q)*68 + row] = wv[q];
    }
  }
  __syncthreads();

  const int tm = tid & 15, tn = tid >> 4;
  float acc[4][4] = {};
  #pragma unroll 8
  for (int k=0;k<64;k++) {
    float4 a  = *(const float4*)&sX[k*68 + tm*4];
    float4 bb = *(const float4*)&sA[k*68 + tn*4];
    float av[4]={a.x,a.y,a.z,a.w}, bv[4]={bb.x,bb.y,bb.z,bb.w};
    #pragma unroll
    for (int i=0;i<4;i++)
      #pragma unroll
      for (int j=0;j<4;j++)
        acc[i][j] = fmaf(av[i], bv[j], acc[i][j]);
  }

  float cv[4];
  #pragma unroll
  for (int j=0;j<4;j++) cv[j] = constv[g0 + tn*4 + j];
  #pragma unroll
  for (int i=0;i<4;i++) {
    int mrow = m0 + tm*4 + i;
    #pragma unroll
    for (int j=0;j<4;j++)
      xp[mrow*384 + g0 + tn*4 + j] = acc[i][j] + cv[j];
  }
}

// ---------------------------------------------------------------------------
// K5: biGRU recurrence, register-only. 128 blocks = (b,dir), ONE wave.
// Lane g owns hidden unit g; h stays in a VGPR. Broadcast via v_readlane of
// fp16-packed pairs (no LDS, no barriers). Weights resident as fp16 pairs
// (96 VGPRs); matvec = 96 v_dot2_f32_f16 (fp16 mul, fp32 accumulate).
// xp prefetch depth-2 with named registers (no rotation).
// ---------------------------------------------------------------------------
__global__ __launch_bounds__(64, 1) void k5_gru(
    const float* __restrict__ xp,
    const float* __restrict__ Whh_f, const float* __restrict__ bhh_f,
    const float* __restrict__ Whh_b, const float* __restrict__ bhh_b,
    float* __restrict__ gru_out)
{
  const int bd = blockIdx.x;
  const int b = bd >> 1, dir = bd & 1;
  const int g = threadIdx.x & 63;
  const float* Whh = dir ? Whh_b : Whh_f;
  const float* bhh = dir ? bhh_b : bhh_f;

  // resident fp16-packed weight rows (one gate row per gate, this lane's unit)
  h2v wr[32], wz[32], wn[32];
  #pragma unroll
  for (int i=0;i<32;i++){
    float2 a = ((const float2*)(Whh + (size_t)g*64))[i];
    float2 bq= ((const float2*)(Whh + (size_t)(64+g)*64))[i];
    float2 c = ((const float2*)(Whh + (size_t)(128+g)*64))[i];
    wr[i] = h2v{(_Float16)a.x, (_Float16)a.y};
    wz[i] = h2v{(_Float16)bq.x,(_Float16)bq.y};
    wn[i] = h2v{(_Float16)c.x, (_Float16)c.y};
  }
  const float br_ = bhh[g], bz_ = bhh[64+g], bn_ = bhh[128+g];

  const int t0 = dir ? (Tt-1) : 0;
  const int tstep = dir ? -1 : 1;
  const float* xb = xp + (size_t)(b*Tt)*384 + dir*192 + g;
  float* gout = gru_out + (size_t)(b*Tt)*128 + dir*64 + g;

  float h = 0.f;
  float xrA = xb[(size_t)t0*384], xzA = xb[(size_t)t0*384+64], xnA = xb[(size_t)t0*384+128];
  const int t1 = t0 + tstep;
  float xrB = xb[(size_t)t1*384], xzB = xb[(size_t)t1*384+64], xnB = xb[(size_t)t1*384+128];

  int t = t0;
  auto STEP = [&](float& xr, float& xz, float& xn){
    // pack {h[2i], h[2i+1]} as fp16 pair (valid on even lanes; we only
    // readlane even lanes)
    float nb = __shfl_xor(h, 1, 64);
    h2v hp; hp[0] = (_Float16)h; hp[1] = (_Float16)nb;
    const int hpk = __builtin_bit_cast(int, hp);

    float ar0=0.f,ar1=0.f,az0=0.f,az1=0.f,an0=0.f,an1=0.f;
    #pragma unroll
    for (int i=0;i<32;i+=2){
      int p0 = __builtin_amdgcn_readlane(hpk, 2*i);
      int p1 = __builtin_amdgcn_readlane(hpk, 2*i+2);
      h2v h0 = __builtin_bit_cast(h2v, p0);
      h2v h1 = __builtin_bit_cast(h2v, p1);
      ar0 = DOT2(wr[i],  h0, ar0);  az0 = DOT2(wz[i],  h0, az0);  an0 = DOT2(wn[i],  h0, an0);
      ar1 = DOT2(wr[i+1],h1, ar1);  az1 = DOT2(wz[i+1],h1, az1);  an1 = DOT2(wn[i+1],h1, an1);
    }

    const float cxr = xr, cxz = xz, cxn = xn;
    const int tpre = t + 2*tstep;
    if ((unsigned)tpre < (unsigned)Tt) {   // depth-2 prefetch, reload after use
      xr = xb[(size_t)tpre*384];
      xz = xb[(size_t)tpre*384+64];
      xn = xb[(size_t)tpre*384+128];
    }

    float r   = sigm(cxr + (ar0+ar1) + br_);
    float z   = sigm(cxz + (az0+az1) + bz_);
    float nn2 = tanh_fast(cxn + r*((an0+an1) + bn_));
    float hnew = (1.f - z)*nn2 + z*h;
    h = hnew;
    gout[(size_t)t*128] = hnew;
    t += tstep;
  };

  for (int sp=0; sp<Tt; sp+=2) { STEP(xrA,xzA,xnA); STEP(xrB,xzB,xnB); }
}

// ---------------------------------------------------------------------------
// K6: attention pooling + classifier. One block per batch item.
// ---------------------------------------------------------------------------
__global__ __launch_bounds__(256) void k6_attn(
    const float* __restrict__ gru_out,
    const float* __restrict__ attn_W, const float* __restrict__ attn_b,
    const float* __restrict__ clf_W,  const float* __restrict__ clf_b,
    float* __restrict__ out)
{
  const int b = blockIdx.x, tid = threadIdx.x;
  __shared__ float s_s[Tt];
  __shared__ float red[256];
  __shared__ float aW[128], cW[128];
  if (tid < 128) { aW[tid]=attn_W[tid]; cW[tid]=clf_W[tid]; }
  __syncthreads();

  if (tid < Tt) {
    const float* row = gru_out + (b*Tt + tid)*128;
    float acc = 0.f;
    for (int j=0;j<128;j++) acc = fmaf(row[j], aW[j], acc);
    s_s[tid] = tanhf(acc + attn_b[0]);
  }
  __syncthreads();

  red[tid] = (tid < Tt) ? s_s[tid] : -1e30f;
  __syncthreads();
  for (int s2=128;s2;s2>>=1){ if(tid<s2) red[tid]=fmaxf(red[tid],red[tid+s2]); __syncthreads(); }
  float mx = red[0];
  __syncthreads();

  float e = 0.f;
  if (tid < Tt) { e = expf(s_s[tid]-mx); s_s[tid] = e; }
  red[tid] = e;
  __syncthreads();
  for (int s2=128;s2;s2>>=1){ if(tid<s2) red[tid]+=red[tid+s2]; __syncthreads(); }
  float total = red[0];
  __syncthreads();

  float p = 0.f;
  if (tid < 128) {
    float c = 0.f;
    for (int t=0;t<Tt;t++) c = fmaf(s_s[t], gru_out[(b*Tt+t)*128 + tid], c);
    p = (c/total)*cW[tid];
  }
  red[tid] = p;
  __syncthreads();
  for (int s2=128;s2;s2>>=1){ if(tid<s2) red[tid]+=red[tid+s2]; __syncthreads(); }
  if (tid==0) out[b] = sigm(red[0] + clf_b[0]);
}

// ---------------------------------------------------------------------------
extern "C" void kernel_launch(void* const* d_in, const int* in_sizes, int n_in,
                              void* d_out, int out_size, void* d_ws, size_t ws_size,
                              hipStream_t stream)
{
  const float* x      = (const float*)d_in[0];
  const int*   sp_ei  = (const int*)  d_in[1];
  const float* sp_ew  = (const float*)d_in[2];
  const int*   fn_ei  = (const int*)  d_in[3];
  const float* fn_ew  = (const float*)d_in[4];
  const float* Wcheb  = (const float*)d_in[5];
  const float* bcheb  = (const float*)d_in[6];
  const float* Wgcn   = (const float*)d_in[7];
  const float* bgcn   = (const float*)d_in[8];
  const float* Wih_f  = (const float*)d_in[9];
  const float* Whh_f  = (const float*)d_in[10];
  const float* bih_f  = (const float*)d_in[11];
  const float* bhh_f  = (const float*)d_in[12];
  const float* Wih_b  = (const float*)d_in[13];
  const float* Whh_b  = (const float*)d_in[14];
  const float* bih_b  = (const float*)d_in[15];
  const float* bhh_b  = (const float*)d_in[16];
  const float* attn_W = (const float*)d_in[17];
  const float* attn_b = (const float*)d_in[18];
  const float* clf_W  = (const float*)d_in[19];
  const float* clf_b  = (const float*)d_in[20];
  float* out = (float*)d_out;

  float* ws     = (float*)d_ws;
  float* Lg     = ws;                    // 4096
  float* L2g    = Lg   + 4096;           // 4096
  float* Gm     = L2g  + 4096;           // 4096
  float* Aeff   = Gm   + 4096;           // 384*64 = 24576
  float* constv = Aeff + 24576;          // 384 (+pad to 512)
  float* xTr    = constv + 512;          // 12800*64 = 819200
  float* xp     = xTr  + 819200;         // 12800*384 = 4915200
  float* gro    = xp   + 4915200;        // 12800*128 = 1638400

  hipLaunchKernelGGL(k1_graphs,    dim3(1),      dim3(256), 0, stream,
                     sp_ei, sp_ew, fn_ei, fn_ew, Lg, L2g, Gm);
  hipLaunchKernelGGL(k3_transpose, dim3(64),     dim3(256), 0, stream, x, xTr);
  hipLaunchKernelGGL(k2_aeff,      dim3(384),    dim3(64),  0, stream,
                     Wih_f, bih_f, Wih_b, bih_b, Wcheb, bcheb, Wgcn, bgcn,
                     Lg, L2g, Gm, Aeff, constv);
  hipLaunchKernelGGL(k4_gemm,      dim3(200, 6), dim3(256), 0, stream,
                     xTr, Aeff, constv, xp);
  hipLaunchKernelGGL(k5_gru,       dim3(128),    dim3(64),  0, stream,
                     xp, Whh_f, bhh_f, Whh_b, bhh_b, gro);
  hipLaunchKernelGGL(k6_attn,      dim3(64),     dim3(256), 0, stream,
                     gro, attn_W, attn_b, clf_W, clf_b, out);
}

// Round 7
// 165.711 us; speedup vs baseline: 1.0241x; 1.0196x over previous
//
#include <hip/hip_runtime.h>
#include <math.h>

#define Nn 64
#define Tt 200
#define Bb 64

__device__ __forceinline__ float sigm(float x){ return 1.0f/(1.0f+__expf(-x)); }
__device__ __forceinline__ float tanh_fast(float x){
  x = fminf(fmaxf(x, -15.f), 15.f);
  float e = __expf(-2.f*x);
  return (1.f - e)/(1.f + e);
}

typedef __attribute__((ext_vector_type(4))) float f4;

// ---------------------------------------------------------------------------
// K1: build graph operators. L = -S_cheb, L2 = 2*S@S - I, G = S_gcn (+diag).
// Single block, 256 threads. Edge scatter via LDS atomics; S padded to
// stride 68 so the S@S phase uses conflict-free f4 row reads.
// ---------------------------------------------------------------------------
__global__ __launch_bounds__(256) void k1_graphs(
    const int* __restrict__ sp_ei, const float* __restrict__ sp_ew,
    const int* __restrict__ fn_ei, const float* __restrict__ fn_ew,
    float* __restrict__ Lg, float* __restrict__ L2g, float* __restrict__ Gm)
{
  __shared__ float deg[Nn];
  __shared__ float dinv[Nn];
  __shared__ float S[64*68];            // padded stride 68
  const int tid = threadIdx.x;

  // ---- ChebConv operator (512 edges) ----
  if (tid < Nn) deg[tid] = 0.f;
  for (int i=tid;i<64*68;i+=256) S[i]=0.f;
  __syncthreads();
  for (int e=tid;e<512;e+=256) atomicAdd(&deg[sp_ei[e]], sp_ew[e]);   // deg over row
  __syncthreads();
  if (tid < Nn) dinv[tid] = (deg[tid] > 0.f) ? rsqrtf(deg[tid]) : 0.f;
  __syncthreads();
  for (int e=tid;e<512;e+=256) {
    int r = sp_ei[e], c = sp_ei[512+e];
    atomicAdd(&S[c*68 + r], dinv[r]*sp_ew[e]*dinv[c]);
  }
  __syncthreads();
  for (int i=tid;i<4096;i+=256) Lg[i] = -S[(i>>6)*68 + (i&63)];   // Ltil = -S
  // L2 = 2*S@S - I : thread -> row n = tid>>2, 16 cols at mb=(tid&3)*16
  {
    const int n = tid>>2, mb = (tid&3)*16;
    float a[16];
    #pragma unroll
    for (int q=0;q<16;q++) a[q]=0.f;
    for (int j=0;j<64;j++){
      float snj = S[n*68+j];
      const float4* rj = (const float4*)&S[j*68+mb];
      #pragma unroll
      for (int q=0;q<4;q++){
        float4 v = rj[q];
        a[q*4+0]=fmaf(snj,v.x,a[q*4+0]);
        a[q*4+1]=fmaf(snj,v.y,a[q*4+1]);
        a[q*4+2]=fmaf(snj,v.z,a[q*4+2]);
        a[q*4+3]=fmaf(snj,v.w,a[q*4+3]);
      }
    }
    #pragma unroll
    for (int q=0;q<16;q++){
      int m = mb+q;
      L2g[n*64+m] = 2.f*a[q] - (n==m ? 1.f : 0.f);
    }
  }
  __syncthreads();   // all reads of S done before reuse

  // ---- GCNConv operator (1024 edges) ----
  if (tid < Nn) deg[tid] = 0.f;
  for (int i=tid;i<64*68;i+=256) S[i]=0.f;
  __syncthreads();
  for (int e=tid;e<1024;e+=256) atomicAdd(&deg[fn_ei[1024+e]], fn_ew[e]);  // deg over col
  __syncthreads();
  if (tid < Nn) dinv[tid] = rsqrtf(deg[tid] + 1.f);
  __syncthreads();
  for (int e=tid;e<1024;e+=256) {
    int r = fn_ei[e], c = fn_ei[1024+e];
    atomicAdd(&S[c*68 + r], dinv[r]*fn_ew[e]*dinv[c]);
  }
  __syncthreads();
  if (tid < Nn) S[tid*68 + tid] += dinv[tid]*dinv[tid];     // + diag(1/deg)
  __syncthreads();
  for (int i=tid;i<4096;i+=256) Gm[i] = S[(i>>6)*68 + (i&63)];
}

// ---------------------------------------------------------------------------
// K2: fold Wih (+Wcheb/Wgcn/graph ops) into Aeff[384][64] and constv[384].
// ---------------------------------------------------------------------------
__global__ __launch_bounds__(64) void k2_aeff(
    const float* __restrict__ Wih_f, const float* __restrict__ bih_f,
    const float* __restrict__ Wih_b, const float* __restrict__ bih_b,
    const float* __restrict__ Wcheb, const float* __restrict__ bcheb,
    const float* __restrict__ Wgcn,  const float* __restrict__ bgcn,
    const float* __restrict__ Lg, const float* __restrict__ L2g,
    const float* __restrict__ Gm,
    float* __restrict__ Aeff, float* __restrict__ constv)
{
  const int g = blockIdx.x;                 // 0..383
  const int dir = (g >= 192) ? 1 : 0;
  const int grow = dir ? g - 192 : g;
  const float* Wih = dir ? Wih_b : Wih_f;
  const float* bih = dir ? bih_b : bih_f;

  __shared__ float wrow[64*129];
  __shared__ float arow[256];
  const int tid = threadIdx.x;              // 64 threads = 1 wave

  for (int i = tid; i < 8192; i += 64)
    wrow[(i>>7)*129 + (i&127)] = Wih[grow*8192 + i];
  __syncthreads();

  const int n = tid;
  float a0=0.f,a1=0.f,a2=0.f,a3=0.f,cp=0.f;
  for (int c=0;c<64;c++) {
    float w1 = wrow[n*129 + c];
    a0 = fmaf(w1, Wcheb[c],     a0);
    a1 = fmaf(w1, Wcheb[64+c],  a1);
    a2 = fmaf(w1, Wcheb[128+c], a2);
    cp = fmaf(w1, bcheb[c],     cp);
    float w2 = wrow[n*129 + 64 + c];
    a3 = fmaf(w2, Wgcn[c], a3);
    cp = fmaf(w2, bgcn[c], cp);
  }
  arow[n*4+0]=a0; arow[n*4+1]=a1; arow[n*4+2]=a2; arow[n*4+3]=a3;
  for (int off=32; off; off>>=1) cp += __shfl_down(cp, off, 64);
  if (tid==0) constv[g] = cp + bih[grow];
  __syncthreads();

  const int m = tid;
  float ae = arow[m*4+0];
  for (int nn2=0; nn2<64; nn2++) {
    ae = fmaf(arow[nn2*4+1], Lg [nn2*64+m], ae);
    ae = fmaf(arow[nn2*4+2], L2g[nn2*64+m], ae);
    ae = fmaf(arow[nn2*4+3], Gm [nn2*64+m], ae);
  }
  Aeff[g*64+m] = ae;
}

// ---------------------------------------------------------------------------
// K3: transpose x[B][N][T] -> xTr[B*T][N]
// ---------------------------------------------------------------------------
__global__ __launch_bounds__(256) void k3_transpose(
    const float* __restrict__ x, float* __restrict__ xTr)
{
  const int b = blockIdx.x;
  for (int idx = threadIdx.x; idx < Tt*Nn; idx += 256) {
    int t = idx >> 6, m = idx & 63;
    xTr[(b*Tt + t)*64 + m] = x[(b*64 + m)*Tt + t];
  }
}

// ---------------------------------------------------------------------------
// K4: xp[12800][384] = xTr[12800][64] @ Aeff[384][64]^T + constv
// ---------------------------------------------------------------------------
__global__ __launch_bounds__(256) void k4_gemm(
    const float* __restrict__ xTr, const float* __restrict__ Aeff,
    const float* __restrict__ constv, float* __restrict__ xp)
{
  const int m0 = blockIdx.x*64, g0 = blockIdx.y*64;
  __shared__ float sX[64*68];
  __shared__ float sA[64*68];
  const int tid = threadIdx.x;
  const float4* xTr4 = (const float4*)xTr;
  const float4* A4   = (const float4*)Aeff;

  #pragma unroll
  for (int i=0;i<4;i++) {
    int f = tid + i*256;
    int row = f >> 4, kq = f & 15;
    float4 v = xTr4[(m0+row)*16 + kq];
    float vv[4] = {v.x,v.y,v.z,v.w};
    float4 w = A4[(g0+row)*16 + kq];
    float wv[4] = {w.x,w.y,w.z,w.w};
    #pragma unroll
    for (int q=0;q<4;q++) {
      sX[(kq*4+q)*68 + row] = vv[q];
      sA[(kq*4+q)*68 + row] = wv[q];
    }
  }
  __syncthreads();

  const int tm = tid & 15, tn = tid >> 4;
  float acc[4][4] = {};
  #pragma unroll 8
  for (int k=0;k<64;k++) {
    float4 a  = *(const float4*)&sX[k*68 + tm*4];
    float4 bb = *(const float4*)&sA[k*68 + tn*4];
    float av[4]={a.x,a.y,a.z,a.w}, bv[4]={bb.x,bb.y,bb.z,bb.w};
    #pragma unroll
    for (int i=0;i<4;i++)
      #pragma unroll
      for (int j=0;j<4;j++)
        acc[i][j] = fmaf(av[i], bv[j], acc[i][j]);
  }

  float cv[4];
  #pragma unroll
  for (int j=0;j<4;j++) cv[j] = constv[g0 + tn*4 + j];
  #pragma unroll
  for (int i=0;i<4;i++) {
    int mrow = m0 + tm*4 + i;
    #pragma unroll
    for (int j=0;j<4;j++)
      xp[mrow*384 + g0 + tn*4 + j] = acc[i][j] + cv[j];
  }
}

// ---------------------------------------------------------------------------
// K5: biGRU recurrence. 128 blocks = (b,dir); 256 threads (4 waves).
// Segment-split matvec: lane (u,s)=(l&15,l>>4) of wave w computes PARTIAL
// dots of all 3 gates for hidden unit w*16+u over h[16s..16s+15].
//   - weights: 48 f32/lane (12 f4) -- under the ~64-reg residency ceiling
//     the allocator has honored in R1/R4/R6 (R6's 96-reg request got
//     rematerialized into in-loop reloads; that was the 107us).
//   - cross-segment reduce: __shfl_xor 16/32 (in-wave, no LDS state).
//   - gates computed redundantly on ALL lanes (identical sums) -> no second
//     LDS round trip; s==0 lanes write hnew to double-buffered hbuf.
//   - ONE __syncthreads per step; xp prefetch depth-2 with named regs.
// ---------------------------------------------------------------------------
__global__ __launch_bounds__(256, 1) void k5_gru(
    const float* __restrict__ xp,
    const float* __restrict__ Whh_f, const float* __restrict__ bhh_f,
    const float* __restrict__ Whh_b, const float* __restrict__ bhh_b,
    float* __restrict__ gru_out)
{
  const int bd = blockIdx.x;
  const int b = bd >> 1, dir = bd & 1;
  const int tid = threadIdx.x;
  const int w  = tid >> 6;              // wave 0..3
  const int l  = tid & 63;
  const int u  = l & 15;                // unit-in-wave
  const int s  = l >> 4;                // segment 0..3
  const int ug = w*16 + u;              // global hidden unit 0..63
  const float* Whh = dir ? Whh_b : Whh_f;
  const float* bhh = dir ? bhh_b : bhh_f;

  // resident weights: rows {ug, 64+ug, 128+ug}, cols 16s..16s+15
  f4 wr[4], wz[4], wn[4];
  #pragma unroll
  for (int j=0;j<4;j++){
    wr[j] = ((const f4*)(Whh + (size_t)(      ug)*64 + 16*s))[j];
    wz[j] = ((const f4*)(Whh + (size_t)( 64 + ug)*64 + 16*s))[j];
    wn[j] = ((const f4*)(Whh + (size_t)(128 + ug)*64 + 16*s))[j];
  }
  const float br_ = bhh[ug], bz_ = bhh[64+ug], bn_ = bhh[128+ug];

  __shared__ __align__(16) float hbuf[2][64];
  if (tid < 64) { hbuf[0][tid] = 0.f; hbuf[1][tid] = 0.f; }
  float hprev = 0.f;

  const int t0 = dir ? (Tt-1) : 0;
  const int tstep = dir ? -1 : 1;
  const float* xb = xp + (size_t)(b*Tt)*384 + dir*192 + ug;
  float* gout = gru_out + (size_t)(b*Tt)*128 + dir*64 + ug;

  float xrA = xb[(size_t)t0*384], xzA = xb[(size_t)t0*384+64], xnA = xb[(size_t)t0*384+128];
  const int t1 = t0 + tstep;
  float xrB = xb[(size_t)t1*384], xzB = xb[(size_t)t1*384+64], xnB = xb[(size_t)t1*384+128];
  __syncthreads();                       // hbuf init + first prefetch visible

  int t = t0;
  auto STEP = [&](float& xr, float& xz, float& xn, int rb){
    const f4* hp = (const f4*)&hbuf[rb][16*s];
    float ar=0.f, az=0.f, an=0.f;
    #pragma unroll
    for (int j=0;j<4;j++){
      f4 hv = hp[j];
      ar=fmaf(wr[j].x,hv.x,ar); ar=fmaf(wr[j].y,hv.y,ar);
      ar=fmaf(wr[j].z,hv.z,ar); ar=fmaf(wr[j].w,hv.w,ar);
      az=fmaf(wz[j].x,hv.x,az); az=fmaf(wz[j].y,hv.y,az);
      az=fmaf(wz[j].z,hv.z,az); az=fmaf(wz[j].w,hv.w,az);
      an=fmaf(wn[j].x,hv.x,an); an=fmaf(wn[j].y,hv.y,an);
      an=fmaf(wn[j].z,hv.z,an); an=fmaf(wn[j].w,hv.w,an);
    }
    // cross-segment butterfly: all 4 copies end with the full sums
    ar += __shfl_xor(ar,16,64); az += __shfl_xor(az,16,64); an += __shfl_xor(an,16,64);
    ar += __shfl_xor(ar,32,64); az += __shfl_xor(az,32,64); an += __shfl_xor(an,32,64);

    const float cxr=xr, cxz=xz, cxn=xn;
    const int tpre = t + 2*tstep;
    if ((unsigned)tpre < (unsigned)Tt) {     // depth-2 prefetch, reload after use
      xr = xb[(size_t)tpre*384];
      xz = xb[(size_t)tpre*384+64];
      xn = xb[(size_t)tpre*384+128];
    }

    float r    = sigm(cxr + ar + br_);
    float z    = sigm(cxz + az + bz_);
    float nn2  = tanh_fast(cxn + r*(an + bn_));
    float hnew = (1.f - z)*nn2 + z*hprev;
    hprev = hnew;                            // identical on all 4 copies
    if (s == 0) {
      hbuf[rb^1][ug] = hnew;
      gout[(size_t)t*128] = hnew;
    }
    t += tstep;
    __syncthreads();                         // hnew visible for next step
  };

  for (int sp=0; sp<Tt; sp+=2) { STEP(xrA,xzA,xnA,0); STEP(xrB,xzB,xnB,1); }
}

// ---------------------------------------------------------------------------
// K6: attention pooling + classifier. One block per batch item.
// ---------------------------------------------------------------------------
__global__ __launch_bounds__(256) void k6_attn(
    const float* __restrict__ gru_out,
    const float* __restrict__ attn_W, const float* __restrict__ attn_b,
    const float* __restrict__ clf_W,  const float* __restrict__ clf_b,
    float* __restrict__ out)
{
  const int b = blockIdx.x, tid = threadIdx.x;
  __shared__ float s_s[Tt];
  __shared__ float red[256];
  __shared__ float aW[128], cW[128];
  if (tid < 128) { aW[tid]=attn_W[tid]; cW[tid]=clf_W[tid]; }
  __syncthreads();

  if (tid < Tt) {
    const float* row = gru_out + (b*Tt + tid)*128;
    float acc = 0.f;
    for (int j=0;j<128;j++) acc = fmaf(row[j], aW[j], acc);
    s_s[tid] = tanhf(acc + attn_b[0]);
  }
  __syncthreads();

  red[tid] = (tid < Tt) ? s_s[tid] : -1e30f;
  __syncthreads();
  for (int s2=128;s2;s2>>=1){ if(tid<s2) red[tid]=fmaxf(red[tid],red[tid+s2]); __syncthreads(); }
  float mx = red[0];
  __syncthreads();

  float e = 0.f;
  if (tid < Tt) { e = expf(s_s[tid]-mx); s_s[tid] = e; }
  red[tid] = e;
  __syncthreads();
  for (int s2=128;s2;s2>>=1){ if(tid<s2) red[tid]+=red[tid+s2]; __syncthreads(); }
  float total = red[0];
  __syncthreads();

  float p = 0.f;
  if (tid < 128) {
    float c = 0.f;
    for (int t=0;t<Tt;t++) c = fmaf(s_s[t], gru_out[(b*Tt+t)*128 + tid], c);
    p = (c/total)*cW[tid];
  }
  red[tid] = p;
  __syncthreads();
  for (int s2=128;s2;s2>>=1){ if(tid<s2) red[tid]+=red[tid+s2]; __syncthreads(); }
  if (tid==0) out[b] = sigm(red[0] + clf_b[0]);
}

// ---------------------------------------------------------------------------
extern "C" void kernel_launch(void* const* d_in, const int* in_sizes, int n_in,
                              void* d_out, int out_size, void* d_ws, size_t ws_size,
                              hipStream_t stream)
{
  const float* x      = (const float*)d_in[0];
  const int*   sp_ei  = (const int*)  d_in[1];
  const float* sp_ew  = (const float*)d_in[2];
  const int*   fn_ei  = (const int*)  d_in[3];
  const float* fn_ew  = (const float*)d_in[4];
  const float* Wcheb  = (const float*)d_in[5];
  const float* bcheb  = (const float*)d_in[6];
  const float* Wgcn   = (const float*)d_in[7];
  const float* bgcn   = (const float*)d_in[8];
  const float* Wih_f  = (const float*)d_in[9];
  const float* Whh_f  = (const float*)d_in[10];
  const float* bih_f  = (const float*)d_in[11];
  const float* bhh_f  = (const float*)d_in[12];
  const float* Wih_b  = (const float*)d_in[13];
  const float* Whh_b  = (const float*)d_in[14];
  const float* bih_b  = (const float*)d_in[15];
  const float* bhh_b  = (const float*)d_in[16];
  const float* attn_W = (const float*)d_in[17];
  const float* attn_b = (const float*)d_in[18];
  const float* clf_W  = (const float*)d_in[19];
  const float* clf_b  = (const float*)d_in[20];
  float* out = (float*)d_out;

  float* ws     = (float*)d_ws;
  float* Lg     = ws;                    // 4096
  float* L2g    = Lg   + 4096;           // 4096
  float* Gm     = L2g  + 4096;           // 4096
  float* Aeff   = Gm   + 4096;           // 384*64 = 24576
  float* constv = Aeff + 24576;          // 384 (+pad to 512)
  float* xTr    = constv + 512;          // 12800*64 = 819200
  float* xp     = xTr  + 819200;         // 12800*384 = 4915200
  float* gro    = xp   + 4915200;        // 12800*128 = 1638400

  hipLaunchKernelGGL(k1_graphs,    dim3(1),      dim3(256), 0, stream,
                     sp_ei, sp_ew, fn_ei, fn_ew, Lg, L2g, Gm);
  hipLaunchKernelGGL(k3_transpose, dim3(64),     dim3(256), 0, stream, x, xTr);
  hipLaunchKernelGGL(k2_aeff,      dim3(384),    dim3(64),  0, stream,
                     Wih_f, bih_f, Wih_b, bih_b, Wcheb, bcheb, Wgcn, bgcn,
                     Lg, L2g, Gm, Aeff, constv);
  hipLaunchKernelGGL(k4_gemm,      dim3(200, 6), dim3(256), 0, stream,
                     xTr, Aeff, constv, xp);
  hipLaunchKernelGGL(k5_gru,       dim3(128),    dim3(256), 0, stream,
                     xp, Whh_f, bhh_f, Whh_b, bhh_b, gro);
  hipLaunchKernelGGL(k6_attn,      dim3(64),     dim3(256), 0, stream,
                     gro, attn_W, attn_b, clf_W, clf_b, out);
}